// Round 4
// baseline (257.522 us; speedup 1.0000x reference)
//
#include <hip/hip_runtime.h>

#define NB 8
#define CC 3
#define HH 720
#define WW 1280
#define EPSL 1e-6f
#define HSEG 30            // 720 = 24*30
#define NSEG (HH / HSEG)   // 24
#define G4   (NSEG / 4)    // 6 groups of 4 hsegs (one per wave)
#define OUTC 56            // output cols per wave (64 lanes - 8 halo)
#define NSTRIP 23          // 23*56 = 1288 >= 1280
#define NST  ((HSEG + 8) / 2)    // 19 stages, 2 rows per stage
#define NBLK (NB * NSTRIP * G4)  // 1104 blocks, 4 waves each

#define OFFR(row) ((unsigned)(min(max((row),0),HH-1)*WW + gcc))

// per-row horizontal gather: weights + 6 loads (issued here, waited at use)
#define GATHER(row, dv, w0_, w1_, g00_, g01_, g10_, g11_, g20_, g21_) do { \
    float ix_ = gcf - (dv); float x0f_ = floorf(ix_); float wx_ = ix_ - x0f_; \
    int x0i_ = (int)x0f_; int x1i_ = x0i_ + 1;                              \
    float v0_ = (x0i_ >= 0 && x0i_ < WW) ? 1.f : 0.f;                       \
    float v1_ = (x1i_ >= 0 && x1i_ < WW) ? 1.f : 0.f;                       \
    int i0_ = min(max(x0i_,0),WW-1); int i1_ = min(max(x1i_,0),WW-1);       \
    w0_ = v0_*(1.f-wx_); w1_ = v1_*wx_;                                     \
    unsigned rb_ = (unsigned)(min(max((row),0),HH-1)*WW);                   \
    g00_ = rp0[rb_+i0_]; g01_ = rp0[rb_+i1_];                               \
    g10_ = rp1[rb_+i0_]; g11_ = rp1[rb_+i1_];                               \
    g20_ = rp2[rb_+i0_]; g21_ = rp2[rb_+i1_]; } while(0)

// LCN + loss for one output row; pa..pc = warped centers, la..lc = left centers
#define OUTROW(pa,pb,pc, la,lb,lc) do {                                      \
    float ml_  = vsum.x*(1.f/81.f);                                          \
    float msl_ = vsum.y*(1.f/81.f);                                          \
    float stdl_=(msl_-ml_*ml_)*(81.f/80.f);                                  \
    float sl_=stdl_+EPSL;                                                    \
    float invl_=__builtin_amdgcn_rcpf(sl_);                                  \
    invl_ = invl_*__builtin_fmaf(-sl_,invl_,2.f);                            \
    float mr_  = vsum.z*(1.f/81.f);                                          \
    float msr_ = vsum.w*(1.f/81.f);                                          \
    float stdr_=(msr_-mr_*mr_)*(81.f/80.f);                                  \
    float sr_=stdr_+EPSL;                                                    \
    float invr_=__builtin_amdgcn_rcpf(sr_);                                  \
    invr_ = invr_*__builtin_fmaf(-sr_,invr_,2.f);                            \
    if (out_lane) {                                                          \
        float av_,bv_;                                                       \
        av_=((la)-ml_)*invl_; bv_=((pa)-mr_)*invr_;                          \
        acc += fabsf((av_-bv_)*stdl_);                                       \
        av_=((lb)-ml_)*invl_; bv_=((pb)-mr_)*invr_;                          \
        acc += fabsf((av_-bv_)*stdl_);                                       \
        av_=((lc)-ml_)*invl_; bv_=((pc)-mr_)*invr_;                          \
        acc += fabsf((av_-bv_)*stdl_);                                       \
    } } while(0)

__device__ __forceinline__ float bperm(int addr, float x) {
    return __int_as_float(__builtin_amdgcn_ds_bpermute(addr, __float_as_int(x)));
}

__global__ __launch_bounds__(256)
void fused_loss_kernel(const float* __restrict__ left,
                       const float* __restrict__ right,
                       const float* __restrict__ disp,
                       float* __restrict__ out)
{
    const int t    = threadIdx.x;
    const int lane = t & 63;
    const int wid  = t >> 6;

    // block-scalar decode: n, strip uniform per block -> SGPR base pointers
    const int b     = blockIdx.x;
    const int strip = b % NSTRIP;
    const int g     = (b / NSTRIP) % G4;
    const int n     = b / (NSTRIP * G4);

    const int h0 = (g * 4 + wid) * HSEG;       // per-wave segment
    const int gc  = strip * OUTC + lane - 4;
    const int gcc = min(max(gc, 0), WW - 1);
    const float gcf = (float)gc;
    const bool col_ok   = (gc >= 0) && (gc < WW);
    const bool out_lane = (lane >= 4) && (lane < 4 + OUTC) && (gc < WW);

    const size_t plane = (size_t)HH * WW;
    const float* __restrict__ dp  = disp  + (size_t)n * plane;
    const float* __restrict__ lp0 = left  + (size_t)n * CC * plane;
    const float* __restrict__ lp1 = lp0 + plane;
    const float* __restrict__ lp2 = lp1 + plane;
    const float* __restrict__ rp0 = right + (size_t)n * CC * plane;
    const float* __restrict__ rp1 = rp0 + plane;
    const float* __restrict__ rp2 = rp1 + plane;

    const int a_m1 = ((lane + 63) & 63) << 2;
    const int a_p1 = ((lane +  1) & 63) << 2;
    const int a_m3 = ((lane + 61) & 63) << 2;
    const int a_p3 = ((lane +  3) & 63) << 2;

    // h-row ring, delay 4 stages (= 8 rows), 2 float4 per thread per slot
    __shared__ float4 ringA[4][256];   // 16 KiB
    __shared__ float4 ringB[4][256];   // 16 KiB

    const int r0 = h0 - 4;

    // ---- prologue ----
    // packet A: rows r0, r0+1 (left values; disp consumed by GATHER below)
    unsigned oA0 = OFFR(r0), oA1 = OFFR(r0 + 1);
    float dA0 = dp[oA0], lA00 = lp0[oA0], lA01 = lp1[oA0], lA02 = lp2[oA0];
    float dA1 = dp[oA1], lA10 = lp0[oA1], lA11 = lp1[oA1], lA12 = lp2[oA1];
    // packet N: rows r0+2, r0+3
    unsigned oN0 = OFFR(r0 + 2), oN1 = OFFR(r0 + 3);
    float dN0 = dp[oN0], lN00 = lp0[oN0], lN01 = lp1[oN0], lN02 = lp2[oN0];
    float dN1 = dp[oN1], lN10 = lp0[oN1], lN11 = lp1[oN1], lN12 = lp2[oN1];
    // gathers for packet A rows
    float wA00,wA01, gA00,gA01,gA10,gA11,gA20,gA21;
    float wA10,wA11, gB00,gB01,gB10,gB11,gB20,gB21;
    GATHER(r0,     dA0, wA00,wA01, gA00,gA01,gA10,gA11,gA20,gA21);
    GATHER(r0 + 1, dA1, wA10,wA11, gB00,gB01,gB10,gB11,gB20,gB21);

    // warped-center chain, depth 2 stages (rows pair)
    float c1a0=0,c1b0=0,c1c0=0, c1a1=0,c1b1=0,c1c1=0;
    float c2a0=0,c2b0=0,c2c0=0, c2a1=0,c2b1=0,c2c1=0;

    float4 vsum = make_float4(0.f,0.f,0.f,0.f);
    float acc = 0.f;

    for (int k = 0; k < NST; ++k) {
        const int x0 = r0 + 2*k;          // first row of this stage
        const int s  = k & 3;

        // (0) ring read: pair pushed 4 stages (8 rows) ago
        float4 old0 = ringA[s][t];
        float4 old1 = ringB[s][t];

        // (1) left reload for this stage's two output rows (L2-hot)
        unsigned oO0 = OFFR(x0 - 4), oO1 = OFFR(x0 - 3);
        float ol00 = lp0[oO0], ol01 = lp1[oO0], ol02 = lp2[oO0];
        float ol10 = lp0[oO1], ol11 = lp1[oO1], ol12 = lp2[oO1];

        // (2) LD(k+2): rows x0+4, x0+5 (consumed in 2 stages)
        unsigned oM0 = OFFR(x0 + 4), oM1 = OFFR(x0 + 5);
        float dM0 = dp[oM0], lM00 = lp0[oM0], lM01 = lp1[oM0], lM02 = lp2[oM0];
        float dM1 = dp[oM1], lM10 = lp0[oM1], lM11 = lp1[oM1], lM12 = lp2[oM1];

        // (3) GT(k+1): gathers for rows x0+2, x0+3 using dN (loaded last stage)
        float wN00,wN01, ng00,ng01,ng10,ng11,ng20,ng21;
        float wN10,wN11, nh00,nh01,nh10,nh11,nh20,nh21;
        GATHER(x0 + 2, dN0, wN00,wN01, ng00,ng01,ng10,ng11,ng20,ng21);
        GATHER(x0 + 3, dN1, wN10,wN11, nh00,nh01,nh10,nh11,nh20,nh21);

        // (4) combine rows x0, x1 (gathers issued last stage)
        float rca0 = gA00*wA00 + gA01*wA01;
        float rcb0 = gA10*wA00 + gA11*wA01;
        float rcc0 = gA20*wA00 + gA21*wA01;
        float rca1 = gB00*wA10 + gB01*wA11;
        float rcb1 = gB10*wA10 + gB11*wA11;
        float rcc1 = gB20*wA10 + gB21*wA11;
        bool val0 = col_ok && ((unsigned)x0       < (unsigned)HH);
        bool val1 = col_ok && ((unsigned)(x0 + 1) < (unsigned)HH);
        float rx0 = lA00+lA01+lA02, ry0 = lA00*lA00+lA01*lA01+lA02*lA02;
        float rz0 = rca0+rcb0+rcc0, rw0 = rca0*rca0+rcb0*rcb0+rcc0*rcc0;
        float rx1 = lA10+lA11+lA12, ry1 = lA10*lA10+lA11*lA11+lA12*lA12;
        float rz1 = rca1+rcb1+rcc1, rw1 = rca1*rca1+rcb1*rcb1+rcc1*rcc1;
        rx0 = val0 ? rx0 : 0.f; ry0 = val0 ? ry0 : 0.f;
        rz0 = val0 ? rz0 : 0.f; rw0 = val0 ? rw0 : 0.f;
        rx1 = val1 ? rx1 : 0.f; ry1 = val1 ? ry1 : 0.f;
        rz1 = val1 ? rz1 : 0.f; rw1 = val1 ? rw1 : 0.f;

        // (5) horizontal 9-sum trees, both rows: level-1 (16 bperms, 1 wait)
        float sx0 = bperm(a_m1,rx0) + rx0 + bperm(a_p1,rx0);
        float sy0 = bperm(a_m1,ry0) + ry0 + bperm(a_p1,ry0);
        float sz0 = bperm(a_m1,rz0) + rz0 + bperm(a_p1,rz0);
        float sw0 = bperm(a_m1,rw0) + rw0 + bperm(a_p1,rw0);
        float sx1 = bperm(a_m1,rx1) + rx1 + bperm(a_p1,rx1);
        float sy1 = bperm(a_m1,ry1) + ry1 + bperm(a_p1,ry1);
        float sz1 = bperm(a_m1,rz1) + rz1 + bperm(a_p1,rz1);
        float sw1 = bperm(a_m1,rw1) + rw1 + bperm(a_p1,rw1);
        // level-2 (16 bperms, 1 wait)
        float hx0 = bperm(a_m3,sx0) + sx0 + bperm(a_p3,sx0);
        float hy0 = bperm(a_m3,sy0) + sy0 + bperm(a_p3,sy0);
        float hz0 = bperm(a_m3,sz0) + sz0 + bperm(a_p3,sz0);
        float hw0 = bperm(a_m3,sw0) + sw0 + bperm(a_p3,sw0);
        float hx1 = bperm(a_m3,sx1) + sx1 + bperm(a_p3,sx1);
        float hy1 = bperm(a_m3,sy1) + sy1 + bperm(a_p3,sy1);
        float hz1 = bperm(a_m3,sz1) + sz1 + bperm(a_p3,sz1);
        float hw1 = bperm(a_m3,sw1) + sw1 + bperm(a_p3,sw1);

        float4 h0v = make_float4(hx0,hy0,hz0,hw0);
        float4 h1v = make_float4(hx1,hy1,hz1,hw1);
        ringA[s][t] = h0v;
        ringB[s][t] = h1v;

        // (6) vertical rolling window + outputs (rows x0-4, x0-3)
        vsum.x += h0v.x; vsum.y += h0v.y; vsum.z += h0v.z; vsum.w += h0v.w;
        if (k >= 4) {
            OUTROW(c2a0,c2b0,c2c0, ol00,ol01,ol02);
            vsum.x -= old0.x; vsum.y -= old0.y; vsum.z -= old0.z; vsum.w -= old0.w;
        }
        vsum.x += h1v.x; vsum.y += h1v.y; vsum.z += h1v.z; vsum.w += h1v.w;
        if (k >= 4) {
            OUTROW(c2a1,c2b1,c2c1, ol10,ol11,ol12);
            vsum.x -= old1.x; vsum.y -= old1.y; vsum.z -= old1.z; vsum.w -= old1.w;
        }

        // (7) shift warped-center chain (depth 2)
        c2a0=c1a0; c2b0=c1b0; c2c0=c1c0; c2a1=c1a1; c2b1=c1b1; c2c1=c1c1;
        c1a0=rca0; c1b0=rcb0; c1c0=rcc0; c1a1=rca1; c1b1=rcb1; c1c1=rcc1;

        // (8) rotate packets: N -> A, M -> N; gathers N -> A
        lA00=lN00; lA01=lN01; lA02=lN02; lA10=lN10; lA11=lN11; lA12=lN12;
        wA00=wN00; wA01=wN01; wA10=wN10; wA11=wN11;
        gA00=ng00; gA01=ng01; gA10=ng10; gA11=ng11; gA20=ng20; gA21=ng21;
        gB00=nh00; gB01=nh01; gB10=nh10; gB11=nh11; gB20=nh20; gB21=nh21;
        dN0=dM0; lN00=lM00; lN01=lM01; lN02=lM02;
        dN1=dM1; lN10=lM10; lN11=lM11; lN12=lM12;
    }

    // ---- reduction: wave shuffle -> LDS -> atomic ----
#pragma unroll
    for (int off = 32; off > 0; off >>= 1)
        acc += __shfl_down(acc, off, 64);
    __syncthreads();                 // all waves done with ring
    float* red = (float*)&ringA[0][0];
    if (lane == 0) red[wid] = acc;
    __syncthreads();
    if (t == 0) {
        float s = red[0] + red[1] + red[2] + red[3];
        const float inv_count = 1.f / ((float)NB * CC * HH * WW);
        atomicAdd(out, s * inv_count);
    }
}

extern "C" void kernel_launch(void* const* d_in, const int* in_sizes, int n_in,
                              void* d_out, int out_size, void* d_ws, size_t ws_size,
                              hipStream_t stream) {
    const float* left  = (const float*)d_in[0];
    const float* right = (const float*)d_in[1];
    const float* disp  = (const float*)d_in[2];
    float* out = (float*)d_out;

    hipMemsetAsync(out, 0, sizeof(float) * out_size, stream);

    hipLaunchKernelGGL(fused_loss_kernel, dim3(NBLK), dim3(256), 0, stream,
                       left, right, disp, out);
}

// Round 5
// 249.245 us; speedup vs baseline: 1.0332x; 1.0332x over previous
//
#include <hip/hip_runtime.h>

#define NB 8
#define CC 3
#define HH 720
#define WW 1280
#define EPSL 1e-6f
#define HSEG 15            // 720 = 48*15
#define NSEG (HH / HSEG)   // 48
#define G4   (NSEG / 4)    // 12 groups of 4 hsegs (one per wave)
#define OUTC 56            // output cols per wave (64 lanes - 8 halo)
#define NSTRIP 23          // 23*56 = 1288 >= 1280
#define NITER (HSEG + 8)   // 23
#define NBLK (NB * NSTRIP * G4)  // 2208 blocks, 4 waves each

__device__ __forceinline__ float bperm(int addr, float x) {
    return __int_as_float(__builtin_amdgcn_ds_bpermute(addr, __float_as_int(x)));
}

__global__ __launch_bounds__(256)
void fused_loss_kernel(const float* __restrict__ left,
                       const float* __restrict__ right,
                       const float* __restrict__ disp,
                       float* __restrict__ out)
{
    const int t    = threadIdx.x;
    const int lane = t & 63;
    const int wid  = t >> 6;

    // ---- block-scalar decode: n and strip are uniform per block ----
    const int b     = blockIdx.x;
    const int strip = b % NSTRIP;
    const int g     = (b / NSTRIP) % G4;
    const int n     = b / (NSTRIP * G4);

    const int h0 = (g * 4 + wid) * HSEG;       // per-wave segment
    const int gc  = strip * OUTC + lane - 4;   // column this lane owns
    const int gcc = min(max(gc, 0), WW - 1);
    const float gcf = (float)gc;
    const bool col_ok   = (gc >= 0) && (gc < WW);
    const bool out_lane = (lane >= 4) && (lane < 4 + OUTC) && (gc < WW);

    // scalar (SGPR) base pointers
    const size_t plane = (size_t)HH * WW;
    const float* __restrict__ dp  = disp  + (size_t)n * plane;
    const float* __restrict__ lp0 = left  + (size_t)n * CC * plane;
    const float* __restrict__ lp1 = lp0 + plane;
    const float* __restrict__ lp2 = lp1 + plane;
    const float* __restrict__ rp0 = right + (size_t)n * CC * plane;
    const float* __restrict__ rp1 = rp0 + plane;
    const float* __restrict__ rp2 = rp1 + plane;

    // hoisted bpermute byte-addresses for the symmetric 3x3 window tree
    const int a_m1 = ((lane + 63) & 63) << 2;
    const int a_p1 = ((lane +  1) & 63) << 2;
    const int a_m3 = ((lane + 61) & 63) << 2;
    const int a_p3 = ((lane +  3) & 63) << 2;

    // vertical rolling ring (h-boxed rows, delay 8) — registers
    float4 rg1 = make_float4(0.f,0.f,0.f,0.f);
    float4 rg2=rg1, rg3=rg1, rg4=rg1, rg5=rg1, rg6=rg1, rg7=rg1, rg8=rg1;
    // center-row pixel chain (delay 4): left c0..c2, warped-right c0..c2
    float p1l0=0,p1l1=0,p1l2=0,p1r0=0,p1r1=0,p1r2=0;
    float p2l0=0,p2l1=0,p2l2=0,p2r0=0,p2r1=0,p2r2=0;
    float p3l0=0,p3l1=0,p3l2=0,p3r0=0,p3r1=0,p3r2=0;
    float p4l0=0,p4l1=0,p4l2=0,p4r0=0,p4r1=0,p4r2=0;

    const int r0 = h0 - 4;

    // ---- prologue: rows r0 and r0+1 ----
    int rcl = min(max(r0, 0), HH - 1);
    unsigned ro = (unsigned)(rcl * WW + gcc);
    float dA  = dp[ro];
    float al0 = lp0[ro], al1 = lp1[ro], al2 = lp2[ro];
    rcl = min(max(r0 + 1, 0), HH - 1);
    unsigned rob = (unsigned)(rcl * WW + gcc);
    float dB  = dp[rob];
    float bl0 = lp0[rob], bl1 = lp1[rob], bl2 = lp2[rob];

    float aw0, aw1, ag00, ag01, ag10, ag11, ag20, ag21;
    {
        float ix  = gcf - dA;
        float x0f = floorf(ix), wx = ix - x0f;
        int x0i = (int)x0f, x1i = x0i + 1;
        float v0 = (x0i >= 0 && x0i < WW) ? 1.f : 0.f;
        float v1 = (x1i >= 0 && x1i < WW) ? 1.f : 0.f;
        int i0 = min(max(x0i, 0), WW - 1), i1 = min(max(x1i, 0), WW - 1);
        aw0 = v0 * (1.f - wx); aw1 = v1 * wx;
        unsigned rb = (unsigned)(min(max(r0, 0), HH - 1) * WW);
        ag00 = rp0[rb + i0]; ag01 = rp0[rb + i1];
        ag10 = rp1[rb + i0]; ag11 = rp1[rb + i1];
        ag20 = rp2[rb + i0]; ag21 = rp2[rb + i1];
    }

    float4 vsum = make_float4(0.f,0.f,0.f,0.f);
    float acc = 0.f;

    for (int iter = 0; iter < NITER; ++iter) {
        const int r = r0 + iter;

        // (1) issue loads for row r+2 (consumed next iter)
        int rcl2 = min(max(r + 2, 0), HH - 1);
        unsigned ro2 = (unsigned)(rcl2 * WW + gcc);
        float dC  = dp[ro2];
        float cl0 = lp0[ro2], cl1 = lp1[ro2], cl2 = lp2[ro2];

        // (2) issue gathers for row r+1 using dB (loaded last iter)
        float bw0, bw1, bg00, bg01, bg10, bg11, bg20, bg21;
        {
            float ix  = gcf - dB;
            float x0f = floorf(ix), wx = ix - x0f;
            int x0i = (int)x0f, x1i = x0i + 1;
            float v0 = (x0i >= 0 && x0i < WW) ? 1.f : 0.f;
            float v1 = (x1i >= 0 && x1i < WW) ? 1.f : 0.f;
            int i0 = min(max(x0i, 0), WW - 1), i1 = min(max(x1i, 0), WW - 1);
            bw0 = v0 * (1.f - wx); bw1 = v1 * wx;
            unsigned rb = (unsigned)(min(max(r + 1, 0), HH - 1) * WW);
            bg00 = rp0[rb + i0]; bg01 = rp0[rb + i1];
            bg10 = rp1[rb + i0]; bg11 = rp1[rb + i1];
            bg20 = rp2[rb + i0]; bg21 = rp2[rb + i1];
        }

        // (3) combine raw channel sums for row r (gathers issued last iter)
        float rca = ag00*aw0 + ag01*aw1;
        float rcb = ag10*aw0 + ag11*aw1;
        float rcc = ag20*aw0 + ag21*aw1;
        bool valr = col_ok && ((unsigned)r < (unsigned)HH);
        float rx = al0 + al1 + al2;
        float ry = al0*al0 + al1*al1 + al2*al2;
        float rz = rca + rcb + rcc;
        float rw = rca*rca + rcb*rcb + rcc*rcc;
        rx = valr ? rx : 0.f;  ry = valr ? ry : 0.f;
        rz = valr ? rz : 0.f;  rw = valr ? rw : 0.f;

        // (4) horizontal 9-sum via symmetric 3x3 tree: 4 bpermutes/var, depth 2
        float sx = bperm(a_m1, rx) + rx + bperm(a_p1, rx);
        float sy = bperm(a_m1, ry) + ry + bperm(a_p1, ry);
        float sz = bperm(a_m1, rz) + rz + bperm(a_p1, rz);
        float sw = bperm(a_m1, rw) + rw + bperm(a_p1, rw);
        float hx = bperm(a_m3, sx) + sx + bperm(a_p3, sx);
        float hy = bperm(a_m3, sy) + sy + bperm(a_p3, sy);
        float hz = bperm(a_m3, sz) + sz + bperm(a_p3, sz);
        float hw = bperm(a_m3, sw) + sw + bperm(a_p3, sw);

        // (5) vertical rolling add
        vsum.x += hx; vsum.y += hy; vsum.z += hz; vsum.w += hw;

        // (6) output row h = r-4
        if (iter >= 8) {
            float ml   = vsum.x * (1.f / 81.f);
            float msl  = vsum.y * (1.f / 81.f);
            float stdl = (msl - ml * ml) * (81.f / 80.f);
            float sl   = stdl + EPSL;
            float invl = __builtin_amdgcn_rcpf(sl);
            invl = invl * __builtin_fmaf(-sl, invl, 2.f);   // 1 Newton step
            float mr   = vsum.z * (1.f / 81.f);
            float msr  = vsum.w * (1.f / 81.f);
            float stdr = (msr - mr * mr) * (81.f / 80.f);
            float sr   = stdr + EPSL;
            float invr = __builtin_amdgcn_rcpf(sr);
            invr = invr * __builtin_fmaf(-sr, invr, 2.f);
            if (out_lane) {
                float av, bv;
                av = (p4l0 - ml) * invl; bv = (p4r0 - mr) * invr;
                acc += fabsf((av - bv) * stdl);
                av = (p4l1 - ml) * invl; bv = (p4r1 - mr) * invr;
                acc += fabsf((av - bv) * stdl);
                av = (p4l2 - ml) * invl; bv = (p4r2 - mr) * invr;
                acc += fabsf((av - bv) * stdl);
            }
            // (7) subtract h-boxed row pushed 8 iters ago
            vsum.x -= rg8.x; vsum.y -= rg8.y; vsum.z -= rg8.z; vsum.w -= rg8.w;
        }

        // (8) shift rings
        rg8 = rg7; rg7 = rg6; rg6 = rg5; rg5 = rg4; rg4 = rg3; rg3 = rg2; rg2 = rg1;
        rg1 = make_float4(hx, hy, hz, hw);
        p4l0=p3l0; p4l1=p3l1; p4l2=p3l2; p4r0=p3r0; p4r1=p3r1; p4r2=p3r2;
        p3l0=p2l0; p3l1=p2l1; p3l2=p2l2; p3r0=p2r0; p3r1=p2r1; p3r2=p2r2;
        p2l0=p1l0; p2l1=p1l1; p2l2=p1l2; p2r0=p1r0; p2r1=p1r1; p2r2=p1r2;
        p1l0=al0;  p1l1=al1;  p1l2=al2;  p1r0=rca;  p1r1=rcb;  p1r2=rcc;

        // (9) rotate packets: B -> A (row r+1 becomes current), C -> B
        al0=bl0; al1=bl1; al2=bl2;
        aw0=bw0; aw1=bw1;
        ag00=bg00; ag01=bg01; ag10=bg10; ag11=bg11; ag20=bg20; ag21=bg21;
        dB=dC; bl0=cl0; bl1=cl1; bl2=cl2;
    }

    // ---- reduction: wave shuffle -> LDS (4 slots) -> atomic ----
#pragma unroll
    for (int off = 32; off > 0; off >>= 1)
        acc += __shfl_down(acc, off, 64);
    __shared__ float red[4];
    if (lane == 0) red[wid] = acc;
    __syncthreads();
    if (t == 0) {
        float s = red[0] + red[1] + red[2] + red[3];
        const float inv_count = 1.f / ((float)NB * CC * HH * WW);
        atomicAdd(out, s * inv_count);
    }
}

extern "C" void kernel_launch(void* const* d_in, const int* in_sizes, int n_in,
                              void* d_out, int out_size, void* d_ws, size_t ws_size,
                              hipStream_t stream) {
    const float* left  = (const float*)d_in[0];
    const float* right = (const float*)d_in[1];
    const float* disp  = (const float*)d_in[2];
    float* out = (float*)d_out;

    hipMemsetAsync(out, 0, sizeof(float) * out_size, stream);

    hipLaunchKernelGGL(fused_loss_kernel, dim3(NBLK), dim3(256), 0, stream,
                       left, right, disp, out);
}